// Round 1
// baseline (77.363 us; speedup 1.0000x reference)
//
#include <hip/hip_runtime.h>

#define NUM_STEPS 25
#define THREADS 256

// One thread per sample. Per-block: cooperatively build the 8-entry MLP LUT
// in LDS (input is a 3-bit spike vector -> only 8 possible MLP inputs).
__global__ __launch_bounds__(THREADS) void snn_lut_kernel(
    const float* __restrict__ x,
    const float* __restrict__ W1, const float* __restrict__ b1,
    const float* __restrict__ W2, const float* __restrict__ b2,
    const float* __restrict__ W3, const float* __restrict__ b3,
    const float* __restrict__ W4, const float* __restrict__ b4,
    float* __restrict__ out, int B)
{
    __shared__ float h1s[8][30];
    __shared__ float h2s[8][32];   // +2 pad, keeps rows bank-shifted
    __shared__ float h3s[8][3];
    __shared__ float2 lut[8];

    const int tid = threadIdx.x;

    // ---- Build LUT: layer-parallel, 240 threads do 8 patterns x 30 units ----
    if (tid < 240) {
        const int p = tid / 30, h = tid % 30;
        const float i0 = (float)(p & 1);
        const float i1 = (float)((p >> 1) & 1);
        const float i2 = (float)((p >> 2) & 1);
        float v = W1[h * 3 + 0] * i0 + W1[h * 3 + 1] * i1 + W1[h * 3 + 2] * i2 + b1[h];
        h1s[p][h] = fmaxf(v, 0.0f);
    }
    __syncthreads();
    if (tid < 240) {
        const int p = tid / 30, h = tid % 30;
        float v = b2[h];
        #pragma unroll
        for (int k = 0; k < 30; ++k) v += W2[h * 30 + k] * h1s[p][k];
        h2s[p][h] = fmaxf(v, 0.0f);
    }
    __syncthreads();
    if (tid < 24) {
        const int p = tid / 3, h = tid % 3;
        float v = b3[h];
        #pragma unroll
        for (int k = 0; k < 30; ++k) v += W3[h * 30 + k] * h2s[p][k];
        h3s[p][h] = fmaxf(v, 0.0f);
    }
    __syncthreads();
    if (tid < 8) {
        const int p = tid;
        float o0 = b4[0], o1 = b4[1];
        #pragma unroll
        for (int k = 0; k < 3; ++k) {
            o0 += W4[0 * 3 + k] * h3s[p][k];
            o1 += W4[1 * 3 + k] * h3s[p][k];
        }
        o0 = fmaxf(o0, 0.0f);
        o1 = fmaxf(o1, 0.0f);
        const float e0 = expf(o0), e1 = expf(o1);
        const float inv = 1.0f / (e0 + e1);
        lut[p] = make_float2(e0 * inv, e1 * inv);
    }
    __syncthreads();

    // ---- Per-sample LIF recurrence + LUT accumulation ----
    const int b = blockIdx.x * THREADS + tid;
    if (b >= B) return;

    float xv[9], m[9];
    #pragma unroll
    for (int c = 0; c < 9; ++c) {
        xv[c] = x[b * 9 + c];
        m[c] = 0.0f;
    }

    float acc0 = 0.0f, acc1 = 0.0f;
    for (int t = 0; t < NUM_STEPS; ++t) {
        int s[9];
        #pragma unroll
        for (int c = 0; c < 9; ++c) {
            // reset from PREVIOUS mem's spike; exact left-to-right fp32 ops
            // (no FMA contraction) so the > 1.0 decisions match the reference.
            const float r = (m[c] > 1.0f) ? 1.0f : 0.0f;
            m[c] = __fsub_rn(__fadd_rn(__fmul_rn(0.95f, m[c]), xv[c]), r);
            s[c] = (m[c] > 1.0f) ? 1 : 0;
        }
        // rows of the 3x3 grid
        const int p0 = s[0] | (s[1] << 1) | (s[2] << 2);
        const int p1 = s[3] | (s[4] << 1) | (s[5] << 2);
        const int p2 = s[6] | (s[7] << 1) | (s[8] << 2);
        // cols (swapaxes): bit k of col j is spk[3k + j]
        const int p3 = s[0] | (s[3] << 1) | (s[6] << 2);
        const int p4 = s[1] | (s[4] << 1) | (s[7] << 2);
        const int p5 = s[2] | (s[5] << 1) | (s[8] << 2);

        const float2 l0 = lut[p0], l1 = lut[p1], l2 = lut[p2];
        const float2 l3 = lut[p3], l4 = lut[p4], l5 = lut[p5];
        acc0 += l0.x + l1.x + l2.x + l3.x + l4.x + l5.x;
        acc1 += l0.y + l1.y + l2.y + l3.y + l4.y + l5.y;
    }

    // out is [B, 2] row-major
    out[b * 2 + 0] = acc0;
    out[b * 2 + 1] = acc1;
}

extern "C" void kernel_launch(void* const* d_in, const int* in_sizes, int n_in,
                              void* d_out, int out_size, void* d_ws, size_t ws_size,
                              hipStream_t stream) {
    const float* x  = (const float*)d_in[0];
    const float* W1 = (const float*)d_in[1];
    const float* b1 = (const float*)d_in[2];
    const float* W2 = (const float*)d_in[3];
    const float* b2 = (const float*)d_in[4];
    const float* W3 = (const float*)d_in[5];
    const float* b3 = (const float*)d_in[6];
    const float* W4 = (const float*)d_in[7];
    const float* b4 = (const float*)d_in[8];
    float* out = (float*)d_out;

    const int B = in_sizes[0] / 9;
    const int blocks = (B + THREADS - 1) / THREADS;
    snn_lut_kernel<<<blocks, THREADS, 0, stream>>>(
        x, W1, b1, W2, b2, W3, b3, W4, b4, out, B);
}

// Round 2
// 75.482 us; speedup vs baseline: 1.0249x; 1.0249x over previous
//
#include <hip/hip_runtime.h>

#define NUM_STEPS 25
#define THREADS 256

// One thread per sample (B = 32768). The MLP input is a 3-bit spike vector,
// so the whole 3->30->30->3->2 MLP + softmax collapses to an 8-entry float2
// LUT, built cooperatively per block. The 25-step LIF loop accumulates a
// bit-sliced histogram (8 patterns x 8-bit counters in one uint64; max count
// 150 < 256), so the hot loop touches no memory at all.
__global__ __launch_bounds__(THREADS) void snn_lut_kernel(
    const float* __restrict__ x,
    const float* __restrict__ W1, const float* __restrict__ b1,
    const float* __restrict__ W2, const float* __restrict__ b2,
    const float* __restrict__ W3, const float* __restrict__ b3,
    const float* __restrict__ W4, const float* __restrict__ b4,
    float* __restrict__ out, int B)
{
    __shared__ float h1s[8][30];
    __shared__ float h2s[8][32];          // +2 pad keeps rows bank-shifted
    __shared__ float h3s[8][3];
    __shared__ float2 lut[8];
    __shared__ float xs[THREADS * 9];     // staged x, conflict-free access

    const int tid = threadIdx.x;
    const int blk0 = blockIdx.x * THREADS;

    // ---- Coalesced stage of x: stride-1 global loads -> LDS ----
    {
        const float* xb = x + (size_t)blk0 * 9;
        #pragma unroll
        for (int k = 0; k < 9; ++k) {
            const int i = tid + k * THREADS;           // contiguous across lanes
            xs[i] = xb[i];
        }
    }

    // ---- Build LUT: layer-parallel, 240 threads = 8 patterns x 30 units ----
    if (tid < 240) {
        const int p = tid / 30, h = tid % 30;
        const float i0 = (float)(p & 1);
        const float i1 = (float)((p >> 1) & 1);
        const float i2 = (float)((p >> 2) & 1);
        float v = W1[h * 3 + 0] * i0 + W1[h * 3 + 1] * i1 + W1[h * 3 + 2] * i2 + b1[h];
        h1s[p][h] = fmaxf(v, 0.0f);
    }
    __syncthreads();                                   // h1s + xs visible
    if (tid < 240) {
        const int p = tid / 30, h = tid % 30;
        float v = b2[h];
        #pragma unroll
        for (int k = 0; k < 30; ++k) v += W2[h * 30 + k] * h1s[p][k];
        h2s[p][h] = fmaxf(v, 0.0f);
    }
    __syncthreads();
    if (tid < 24) {
        const int p = tid / 3, h = tid % 3;
        float v = b3[h];
        #pragma unroll
        for (int k = 0; k < 30; ++k) v += W3[h * 30 + k] * h2s[p][k];
        h3s[p][h] = fmaxf(v, 0.0f);
    }
    __syncthreads();
    if (tid < 8) {
        const int p = tid;
        float o0 = b4[0], o1 = b4[1];
        #pragma unroll
        for (int k = 0; k < 3; ++k) {
            o0 += W4[0 * 3 + k] * h3s[p][k];
            o1 += W4[1 * 3 + k] * h3s[p][k];
        }
        o0 = fmaxf(o0, 0.0f);
        o1 = fmaxf(o1, 0.0f);
        const float e0 = expf(o0), e1 = expf(o1);
        const float inv = 1.0f / (e0 + e1);
        lut[p] = make_float2(e0 * inv, e1 * inv);
    }
    // NOTE: no sync here — lut is only read AFTER the main loop.

    // ---- Per-sample LIF recurrence, histogram accumulation (no memory) ----
    float xv[9], m[9], r[9];
    #pragma unroll
    for (int c = 0; c < 9; ++c) {
        xv[c] = xs[tid * 9 + c];   // stride 9 across lanes: gcd(9,32)=1 -> 2-way max (free)
        m[c] = 0.0f;
        r[c] = 0.0f;
    }

    unsigned long long hist = 0ULL;
    for (int t = 0; t < NUM_STEPS; ++t) {
        int s[9];
        #pragma unroll
        for (int c = 0; c < 9; ++c) {
            // Exact left-to-right fp32 ops (no FMA contraction) so the
            // > 1.0 spike decisions match the numpy reference bit-for-bit.
            m[c] = __fsub_rn(__fadd_rn(__fmul_rn(0.95f, m[c]), xv[c]), r[c]);
            const bool sp = m[c] > 1.0f;
            s[c] = sp ? 1 : 0;
            r[c] = sp ? 1.0f : 0.0f;   // this spike is next step's reset
        }
        // rows of the 3x3 grid
        const int p0 = s[0] | (s[1] << 1) | (s[2] << 2);
        const int p1 = s[3] | (s[4] << 1) | (s[5] << 2);
        const int p2 = s[6] | (s[7] << 1) | (s[8] << 2);
        // cols (swapaxes): bit k of col j is spk[3k + j]
        const int p3 = s[0] | (s[3] << 1) | (s[6] << 2);
        const int p4 = s[1] | (s[4] << 1) | (s[7] << 2);
        const int p5 = s[2] | (s[5] << 1) | (s[8] << 2);

        hist += (1ULL << (p0 << 3)) + (1ULL << (p1 << 3)) + (1ULL << (p2 << 3))
              + (1ULL << (p3 << 3)) + (1ULL << (p4 << 3)) + (1ULL << (p5 << 3));
    }

    __syncthreads();                                   // lut now visible

    float acc0 = 0.0f, acc1 = 0.0f;
    #pragma unroll
    for (int p = 0; p < 8; ++p) {
        const float cnt = (float)((hist >> (p << 3)) & 0xFFULL);
        const float2 l = lut[p];                       // broadcast, no conflict
        acc0 += cnt * l.x;
        acc1 += cnt * l.y;
    }

    const int b = blk0 + tid;
    if (b < B) {
        reinterpret_cast<float2*>(out)[b] = make_float2(acc0, acc1);
    }
}

extern "C" void kernel_launch(void* const* d_in, const int* in_sizes, int n_in,
                              void* d_out, int out_size, void* d_ws, size_t ws_size,
                              hipStream_t stream) {
    const float* x  = (const float*)d_in[0];
    const float* W1 = (const float*)d_in[1];
    const float* b1 = (const float*)d_in[2];
    const float* W2 = (const float*)d_in[3];
    const float* b2 = (const float*)d_in[4];
    const float* W3 = (const float*)d_in[5];
    const float* b3 = (const float*)d_in[6];
    const float* W4 = (const float*)d_in[7];
    const float* b4 = (const float*)d_in[8];
    float* out = (float*)d_out;

    const int B = in_sizes[0] / 9;
    const int blocks = (B + THREADS - 1) / THREADS;
    snn_lut_kernel<<<blocks, THREADS, 0, stream>>>(
        x, W1, b1, W2, b2, W3, b3, W4, b4, out, B);
}